// Round 15
// baseline (682.416 us; speedup 1.0000x reference)
//
#include <hip/hip_runtime.h>
#include <cstdint>
#include <cfloat>

#define IN_DIM 768
#define HID    1024
#define KSEL   20
#define MAXC   64
#define TARGET 24
#define WSCALE 4096.0f
#define INV_WSCALE (1.0f / 4096.0f)
#define DELTA  3e-5f

typedef _Float16 f16x8 __attribute__((ext_vector_type(8)));
typedef float    f32x4 __attribute__((ext_vector_type(4)));

__device__ __forceinline__ void gload_lds16(const void* g, void* l) {
    __builtin_amdgcn_global_load_lds(
        (const __attribute__((address_space(1))) uint32_t*)g,
        (__attribute__((address_space(3))) uint32_t*)l, 16, 0, 0);
}

__device__ __forceinline__ float bfu(ushort u) { return __uint_as_float((uint)u << 16); }

// ---------------- K0: transpose W_dec [768][1024] -> WdTb [1024][768] bf16 (RNE) ----------------
__global__ void k_prep_wdb(const float* __restrict__ Wd, ushort* __restrict__ WdTb) {
    __shared__ float tile[32][33];
    const int j0 = blockIdx.x * 32;
    const int i0 = blockIdx.y * 32;
    const int tx = threadIdx.x;
    const int ty = threadIdx.y;
#pragma unroll
    for (int r = 0; r < 4; ++r)
        tile[ty + r * 8][tx] = Wd[(size_t)(i0 + ty + r * 8) * HID + (j0 + tx)];
    __syncthreads();
#pragma unroll
    for (int r = 0; r < 4; ++r) {
        const float v = tile[tx][ty + r * 8];
        uint u = __float_as_uint(v);
        u += 0x7FFFu + ((u >> 16) & 1u);           // round-to-nearest-even
        WdTb[(size_t)(j0 + ty + r * 8) * IN_DIM + (i0 + tx)] = (ushort)(u >> 16);
    }
}

// ---------------- split kernels: fp32 -> fp16 (W scaled by 4096) ----------------
__global__ __launch_bounds__(256) void k_split_x(const float* __restrict__ x,
                                                 _Float16* __restrict__ xh) {
    const size_t base = ((size_t)blockIdx.x * 256 + threadIdx.x) * 8;
    const float4 a = *(const float4*)(x + base);
    const float4 b = *(const float4*)(x + base + 4);
    f16x8 o;
    o[0] = (_Float16)a.x; o[1] = (_Float16)a.y; o[2] = (_Float16)a.z; o[3] = (_Float16)a.w;
    o[4] = (_Float16)b.x; o[5] = (_Float16)b.y; o[6] = (_Float16)b.z; o[7] = (_Float16)b.w;
    *(f16x8*)(xh + base) = o;
}

__global__ __launch_bounds__(256) void k_split_w(const float* __restrict__ w,
                                                 _Float16* __restrict__ wh) {
    const size_t base = ((size_t)blockIdx.x * 256 + threadIdx.x) * 8;
    const float4 a = *(const float4*)(w + base);
    const float4 b = *(const float4*)(w + base + 4);
    f16x8 o;
    o[0] = (_Float16)(a.x * WSCALE); o[1] = (_Float16)(a.y * WSCALE);
    o[2] = (_Float16)(a.z * WSCALE); o[3] = (_Float16)(a.w * WSCALE);
    o[4] = (_Float16)(b.x * WSCALE); o[5] = (_Float16)(b.y * WSCALE);
    o[6] = (_Float16)(b.z * WSCALE); o[7] = (_Float16)(b.w * WSCALE);
    *(f16x8*)(wh + base) = o;
}

// ---------------- K1: fp16 MFMA encode (round-12 validated: gload_lds for A and B) ----------------
__global__ __launch_bounds__(256) void k_encode_f16(
    const _Float16* __restrict__ xh, const _Float16* __restrict__ wh,
    const float* __restrict__ be, float* __restrict__ h)
{
    __shared__ _Float16 lA[128 * 64];
    __shared__ _Float16 lB[128 * 64];
    const int t   = threadIdx.x;
    const int wid = t >> 6, l = t & 63;
    const int wm  = (wid >> 1) * 64, wn = (wid & 1) * 64;
    const int bn  = blockIdx.x * 128, bm = blockIdx.y * 128;

    const int lr = l >> 3;
    const int sl = (l & 7) ^ lr;
    const _Float16* gA = xh + (size_t)(bm + wid * 32 + lr) * IN_DIM + sl * 8;
    const _Float16* gB = wh + (size_t)(bn + wid * 32 + lr) * IN_DIM + sl * 8;
    char* la0 = (char*)lA + wid * 32 * 128;
    char* lb0 = (char*)lB + wid * 32 * 128;

    f32x4 acc[4][4];
#pragma unroll
    for (int i = 0; i < 4; ++i)
#pragma unroll
        for (int j = 0; j < 4; ++j) acc[i][j] = (f32x4){0.f, 0.f, 0.f, 0.f};

    const int row16 = l & 15, kb = l >> 4;

    for (int kt = 0; kt < IN_DIM; kt += 64) {
        __syncthreads();
#pragma unroll
        for (int i = 0; i < 4; ++i) {
            gload_lds16(gA + (size_t)i * 8 * IN_DIM + kt, la0 + i * 1024);
            gload_lds16(gB + (size_t)i * 8 * IN_DIM + kt, lb0 + i * 1024);
        }
        __syncthreads();

        f16x8 af[4][2], bf[4][2];
#pragma unroll
        for (int f = 0; f < 4; ++f) {
            const int ra = wm + f * 16 + row16;
            const int pa = kb ^ (ra & 7);
            af[f][0] = *(const f16x8*)((const char*)lA + ra * 128 + pa * 16);
            af[f][1] = *(const f16x8*)((const char*)lA + ra * 128 + (pa ^ 4) * 16);
            const int rb = wn + f * 16 + row16;
            const int pb = kb ^ (rb & 7);
            bf[f][0] = *(const f16x8*)((const char*)lB + rb * 128 + pb * 16);
            bf[f][1] = *(const f16x8*)((const char*)lB + rb * 128 + (pb ^ 4) * 16);
        }
#pragma unroll
        for (int kh = 0; kh < 2; ++kh)
#pragma unroll
            for (int fm = 0; fm < 4; ++fm)
#pragma unroll
                for (int fn = 0; fn < 4; ++fn)
                    acc[fm][fn] = __builtin_amdgcn_mfma_f32_16x16x32_f16(
                        af[fm][kh], bf[fn][kh], acc[fm][fn], 0, 0, 0);
    }

    const int col = l & 15, rg = (l >> 4) * 4;
#pragma unroll
    for (int fn = 0; fn < 4; ++fn) {
        const int n = bn + wn + fn * 16 + col;
        const float bias = be[n];
#pragma unroll
        for (int fm = 0; fm < 4; ++fm) {
            const int m0 = bm + wm + fm * 16 + rg;
#pragma unroll
            for (int q = 0; q < 4; ++q)
                h[(size_t)(m0 + q) * HID + n] = fmaxf(fmaf(acc[fm][fn][q], INV_WSCALE, bias), 0.f);
        }
    }
}

// ---------------- K1-fallback: fp32 encode ----------------
__global__ __launch_bounds__(256, 2) void k_encode(
    const float* __restrict__ x, const float* __restrict__ We,
    const float* __restrict__ be, float* __restrict__ h)
{
    __shared__ float lx[16][132];
    __shared__ float lw[16][132];
    const int t  = threadIdx.x;
    const int tx = t & 15;
    const int ty = t >> 4;
    const int bn = blockIdx.x * 128;
    const int bm = blockIdx.y * 128;

    float acc[8][8];
#pragma unroll
    for (int r = 0; r < 8; ++r)
#pragma unroll
        for (int c = 0; c < 8; ++c) acc[r][c] = 0.f;

    const int sk = t & 15;
    const int sm = t >> 4;

    for (int kt = 0; kt < IN_DIM; kt += 16) {
        __syncthreads();
#pragma unroll
        for (int p = 0; p < 8; ++p) {
            const int m = sm + p * 16;
            lx[sk][m] = x [(size_t)(bm + m) * IN_DIM + (kt + sk)];
            lw[sk][m] = We[(size_t)(bn + m) * IN_DIM + (kt + sk)];
        }
        __syncthreads();
#pragma unroll
        for (int kk = 0; kk < 16; ++kk) {
            const float4 xa = *(const float4*)&lx[kk][ty * 8];
            const float4 xb = *(const float4*)&lx[kk][ty * 8 + 4];
            const float4 wa = *(const float4*)&lw[kk][tx * 4];
            const float4 wb = *(const float4*)&lw[kk][tx * 4 + 64];
            const float xf[8] = {xa.x, xa.y, xa.z, xa.w, xb.x, xb.y, xb.z, xb.w};
            const float wf[8] = {wa.x, wa.y, wa.z, wa.w, wb.x, wb.y, wb.z, wb.w};
#pragma unroll
            for (int r = 0; r < 8; ++r)
#pragma unroll
                for (int c = 0; c < 8; ++c)
                    acc[r][c] = fmaf(xf[r], wf[c], acc[r][c]);
        }
    }
#pragma unroll
    for (int r = 0; r < 8; ++r) {
        const size_t row = (size_t)(bm + ty * 8 + r) * HID;
#pragma unroll
        for (int c = 0; c < 4; ++c) {
            h[row + bn + tx * 4 + c]      = fmaxf(acc[r][c]     + be[bn + tx * 4 + c], 0.f);
            h[row + bn + 64 + tx * 4 + c] = fmaxf(acc[r][c + 4] + be[bn + 64 + tx * 4 + c], 0.f);
        }
    }
}

// ---------------- K2a: PERSISTENT wave-per-row select with next-row prefetch ----------------
// Each wave owns RPW consecutive rows. At iteration start it issues row r+1's
// four uint4 loads (16 VGPR, no extra selection state), then runs row r's
// selection — the selection chain hides the next row's HBM latency.
__global__ __launch_bounds__(256, 8) void k_topk(
    float* __restrict__ h,
    const float* __restrict__ x,  const float* __restrict__ We,
    const float* __restrict__ be, float* __restrict__ rec, const int rpw)
{
    const int wid  = threadIdx.x >> 6;
    const int lane = threadIdx.x & 63;
    const int b0   = (blockIdx.x * 4 + wid) * rpw;

    __shared__ float cvF[4][MAXC];
    __shared__ int   cjL[4][MAXC];

    uint4 pk[4];
    {
        const float* hr = h + (size_t)b0 * HID;
#pragma unroll
        for (int q = 0; q < 4; ++q) pk[q] = *(const uint4*)&hr[q * 256 + lane * 4];
    }

#pragma unroll 1
    for (int r = 0; r < rpw; ++r) {
        const int b = b0 + r;
        float* hrow = h + (size_t)b * HID;

        uint keys[4][4];
#pragma unroll
        for (int q = 0; q < 4; ++q) {
            keys[q][0] = pk[q].x; keys[q][1] = pk[q].y;
            keys[q][2] = pk[q].z; keys[q][3] = pk[q].w;
        }
        // prefetch next row (issued before the long selection chain)
        if (r + 1 < rpw) {
            const float* hn = h + (size_t)(b + 1) * HID;
#pragma unroll
            for (int q = 0; q < 4; ++q) pk[q] = *(const uint4*)&hn[q * 256 + lane * 4];
        }

        // ---- Phase A: seeded ballot-bisect threshold: 24 <= count(key>=T) <= 64 ----
        uint mk = 0;
#pragma unroll
        for (int q = 0; q < 4; ++q)
#pragma unroll
            for (int i = 0; i < 4; ++i) mk = max(mk, keys[q][i]);
#pragma unroll
        for (int off = 1; off < 64; off <<= 1)
            mk = max(mk, (uint)__shfl_xor((int)mk, off));

        uint loT = 0u, hiT = mk;
        uint T  = __float_as_uint(0.55f * __uint_as_float(mk));
        bool found = false;
#pragma unroll 1
        for (int it = 0; it < 20; ++it) {
            int c = 0;
#pragma unroll
            for (int q = 0; q < 4; ++q)
#pragma unroll
                for (int i = 0; i < 4; ++i)
                    c += (int)__popcll(__ballot(keys[q][i] >= T));
            if (c >= TARGET && c <= MAXC) { found = true; break; }
            if (c > MAXC) loT = T; else hiT = T;
            if (hiT - loT <= 1u) { T = loT; found = true; break; }
            T = (loT + hiT) >> 1;
        }
        if (!found) T = loT;
        const uint prefix = T;

        // ---- Phase B: compact candidates via shuffle prefix-sum ----
        uint cnt = 0;
#pragma unroll
        for (int q = 0; q < 4; ++q)
#pragma unroll
            for (int i = 0; i < 4; ++i) cnt += (keys[q][i] >= prefix) ? 1u : 0u;
        uint inc = cnt;
#pragma unroll
        for (int off = 1; off < 64; off <<= 1) {
            const uint o = __shfl_up(inc, off);
            if (lane >= off) inc += o;
        }
        const uint base = inc - cnt;
        const int  n    = min((int)__shfl((int)inc, 63), MAXC);
        {
            uint m = 0;
#pragma unroll
            for (int q = 0; q < 4; ++q)
#pragma unroll
                for (int i = 0; i < 4; ++i)
                    if (keys[q][i] >= prefix) {
                        const uint slot = base + m; ++m;
                        if (slot < MAXC) {
                            cvF[wid][slot] = __uint_as_float(keys[q][i]);
                            cjL[wid][slot] = q * 256 + lane * 4 + i;
                        }
                    }
        }
        __builtin_amdgcn_wave_barrier();

        const float myv = (lane < n) ? cvF[wid][lane] : -FLT_MAX;
        const int   myj = (lane < n) ? cjL[wid][lane] : 0x7fffffff;

        // ---- Phase C: 64-lane fp32 bitonic sort, desc by (v, then j asc) ----
        float sv = myv; int sj = myj;
#pragma unroll
        for (int bk = 2; bk <= 64; bk <<= 1) {
#pragma unroll
            for (int bj = bk >> 1; bj >= 1; bj >>= 1) {
                const float pv = __shfl_xor(sv, bj);
                const int   pj = __shfl_xor(sj, bj);
                const bool iLow = (lane & bj) == 0;
                const bool dsc  = (lane & bk) == 0;
                const bool mineFirst = (sv > pv) || (sv == pv && sj < pj);
                if ((dsc == iLow) ? !mineFirst : mineFirst) { sv = pv; sj = pj; }
            }
        }
        const float cv19 = __shfl(sv, KSEL - 1);
        const int   cj19 = __shfl(sj, KSEL - 1);
        const float v20  = __shfl(sv, KSEL);
        const bool  amb  = (cv19 - v20 <= DELTA);

        float* recrow = rec + (size_t)b * (2 * KSEL);
        uint m16 = 0;
        if (!amb) {
            if (lane < KSEL)
                *(float2*)&recrow[lane * 2] = (float2){sv, __int_as_float(sj)};
#pragma unroll
            for (int q = 0; q < 4; ++q)
#pragma unroll
                for (int i = 0; i < 4; ++i) {
                    const float ev = __uint_as_float(keys[q][i]);
                    const int   ej = q * 256 + lane * 4 + i;
                    if (ev > cv19 || (ev == cv19 && ej <= cj19)) m16 |= 1u << (q * 4 + i);
                }
        } else {
            // ---- band-only f64 refine ----
            const bool inB = (lane < n) && (fabsf(myv - cv19) <= DELTA);
            const unsigned long long aMask = __ballot((lane < n) && (myv > cv19 + DELTA));
            const int kneed = KSEL - (int)__popcll(aMask);
            const float* xr = x + (size_t)b * IN_DIM;

            double dm = -1.0;
            unsigned long long bb = __ballot(inB);
#pragma unroll 1
            while (bb) {
                const int s = (int)__ffsll((long long)bb) - 1; bb &= bb - 1ull;
                const int j = __shfl(myj, s);
                const float* wr = We + (size_t)j * IN_DIM;
                double acc = 0.0;
#pragma unroll
                for (int m = 0; m < 12; ++m) {
                    const int k = lane + (m << 6);
                    acc = fma((double)wr[k], (double)xr[k], acc);
                }
#pragma unroll
                for (int off = 1; off < 64; off <<= 1) acc += __shfl_xor(acc, off);
                double v = acc + (double)be[j];
                v = v > 0.0 ? v : 0.0;
                if (lane == s) dm = v;
            }
            int brank = 0;
            unsigned long long bb2 = __ballot(inB);
#pragma unroll 1
            while (bb2) {
                const int s = (int)__ffsll((long long)bb2) - 1; bb2 &= bb2 - 1ull;
                const double ds = __shfl(dm, s);
                const int    js = __shfl(myj, s);
                if (inB && s != lane)
                    brank += (ds > dm || (ds == dm && js < myj)) ? 1 : 0;
            }
            const bool selB = inB && (brank < kneed);
            const unsigned long long selMask = aMask | __ballot(selB);
            if ((selMask >> lane) & 1ull) {
                const int slot = (int)__popcll(selMask & ((1ull << lane) - 1ull));
                *(float2*)&recrow[slot * 2] = (float2){myv, __int_as_float(myj)};
            }
#pragma unroll
            for (int q = 0; q < 4; ++q)
#pragma unroll
                for (int i = 0; i < 4; ++i)
                    if (__uint_as_float(keys[q][i]) > cv19 + DELTA) m16 |= 1u << (q * 4 + i);
            unsigned long long sb = __ballot(selB);
#pragma unroll 1
            while (sb) {
                const int s = (int)__ffsll((long long)sb) - 1; sb &= sb - 1ull;
                const int js = __shfl(myj, s);
                const int d  = js - lane * 4;
                if (d >= 0 && (d & 255) < 4 && (d >> 8) < 4)
                    m16 |= 1u << (((d >> 8) << 2) | (d & 3));
            }
        }

        // ---- Phase D: masked h write (posted stores) ----
#pragma unroll
        for (int q = 0; q < 4; ++q) {
            float ov[4];
#pragma unroll
            for (int i = 0; i < 4; ++i)
                ov[i] = ((m16 >> (q * 4 + i)) & 1u) ? __uint_as_float(keys[q][i]) : 0.f;
            *(float4*)&hrow[q * 256 + lane * 4] = (float4){ov[0], ov[1], ov[2], ov[3]};
        }
        __builtin_amdgcn_wave_barrier();   // order LDS reads before next iteration's writes
    }
}

// ---------------- K2b: record -> gather decode -> recon (chunked loads for ILP) ----------------
__global__ __launch_bounds__(256) void k_decode(
    const float* __restrict__ rec, const ushort* __restrict__ WdTb,
    const float* __restrict__ bd, float* __restrict__ recon)
{
    const int wid  = threadIdx.x >> 6;
    const int lane = threadIdx.x & 63;
    const int b    = blockIdx.x * 4 + wid;
    const float* rrec = rec + (size_t)b * (2 * KSEL);

    float v = 0.f; int jj = 0;
    if (lane < KSEL) {
        const float2 p = *(const float2*)&rrec[lane * 2];
        v = p.x; jj = __float_as_int(p.y);
    }

    f32x4 a0 = {0.f,0.f,0.f,0.f}, a1 = {0.f,0.f,0.f,0.f}, a2 = {0.f,0.f,0.f,0.f};
#pragma unroll
    for (int c = 0; c < 2; ++c) {
        ushort4 w0[10], w1[10], w2[10];
#pragma unroll
        for (int s = 0; s < 10; ++s) {
            const int js = __shfl(jj, c * 10 + s);
            const ushort* wr = WdTb + (size_t)js * IN_DIM + lane * 4;
            w0[s] = *(const ushort4*)wr;
            w1[s] = *(const ushort4*)(wr + 256);
            w2[s] = *(const ushort4*)(wr + 512);
        }
#pragma unroll
        for (int s = 0; s < 10; ++s) {
            const float vs = __shfl(v, c * 10 + s);
            a0[0] = fmaf(vs, bfu(w0[s].x), a0[0]); a0[1] = fmaf(vs, bfu(w0[s].y), a0[1]);
            a0[2] = fmaf(vs, bfu(w0[s].z), a0[2]); a0[3] = fmaf(vs, bfu(w0[s].w), a0[3]);
            a1[0] = fmaf(vs, bfu(w1[s].x), a1[0]); a1[1] = fmaf(vs, bfu(w1[s].y), a1[1]);
            a1[2] = fmaf(vs, bfu(w1[s].z), a1[2]); a1[3] = fmaf(vs, bfu(w1[s].w), a1[3]);
            a2[0] = fmaf(vs, bfu(w2[s].x), a2[0]); a2[1] = fmaf(vs, bfu(w2[s].y), a2[1]);
            a2[2] = fmaf(vs, bfu(w2[s].z), a2[2]); a2[3] = fmaf(vs, bfu(w2[s].w), a2[3]);
        }
    }
    float* rrow = recon + (size_t)b * IN_DIM;
    const float4 bd0 = *(const float4*)&bd[lane * 4];
    const float4 bd1 = *(const float4*)&bd[lane * 4 + 256];
    const float4 bd2 = *(const float4*)&bd[lane * 4 + 512];
    *(float4*)&rrow[lane * 4]       = (float4){a0[0] + bd0.x, a0[1] + bd0.y, a0[2] + bd0.z, a0[3] + bd0.w};
    *(float4*)&rrow[lane * 4 + 256] = (float4){a1[0] + bd1.x, a1[1] + bd1.y, a1[2] + bd1.z, a1[3] + bd1.w};
    *(float4*)&rrow[lane * 4 + 512] = (float4){a2[0] + bd2.x, a2[1] + bd2.y, a2[2] + bd2.z, a2[3] + bd2.w};
}

// ---------------- K2a-fallback: single-row fused select+decode (small-ws path) ----------------
template<int USE_BF>
__global__ __launch_bounds__(256) void k_topk_fused(
    float* __restrict__ h,
    const float* __restrict__ x,  const float* __restrict__ We,
    const float* __restrict__ be,
    const ushort* __restrict__ WdTb, const float* __restrict__ Wd,
    const float* __restrict__ bd, float* __restrict__ recon)
{
    const int wid  = threadIdx.x >> 6;
    const int lane = threadIdx.x & 63;
    const int b    = blockIdx.x * 4 + wid;
    float* hrow = h + (size_t)b * HID;

    __shared__ float  cvF [4][MAXC];
    __shared__ int    cjL [4][MAXC];
    __shared__ double cvD [4][MAXC];
    __shared__ float  selv[4][KSEL];
    __shared__ int    selj[4][KSEL];

    uint keys[4][4];
#pragma unroll
    for (int q = 0; q < 4; ++q) {
        const uint4 k4 = *(const uint4*)&hrow[q * 256 + lane * 4];
        keys[q][0] = k4.x; keys[q][1] = k4.y; keys[q][2] = k4.z; keys[q][3] = k4.w;
    }
    uint mk = 0;
#pragma unroll
    for (int q = 0; q < 4; ++q)
#pragma unroll
        for (int i = 0; i < 4; ++i) mk = max(mk, keys[q][i]);
#pragma unroll
    for (int off = 1; off < 64; off <<= 1)
        mk = max(mk, (uint)__shfl_xor((int)mk, off));

    uint loT = 0u, hiT = mk;
    uint T  = __float_as_uint(0.55f * __uint_as_float(mk));
    bool found = false;
#pragma unroll 1
    for (int it = 0; it < 20; ++it) {
        int c = 0;
#pragma unroll
        for (int q = 0; q < 4; ++q)
#pragma unroll
            for (int i = 0; i < 4; ++i)
                c += (int)__popcll(__ballot(keys[q][i] >= T));
        if (c >= TARGET && c <= MAXC) { found = true; break; }
        if (c > MAXC) loT = T; else hiT = T;
        if (hiT - loT <= 1u) { T = loT; found = true; break; }
        T = (loT + hiT) >> 1;
    }
    if (!found) T = loT;

    uint cnt = 0;
#pragma unroll
    for (int q = 0; q < 4; ++q)
#pragma unroll
        for (int i = 0; i < 4; ++i) cnt += (keys[q][i] >= T) ? 1u : 0u;
    uint inc = cnt;
#pragma unroll
    for (int off = 1; off < 64; off <<= 1) {
        const uint o = __shfl_up(inc, off);
        if (lane >= off) inc += o;
    }
    const uint base = inc - cnt;
    const int  n    = min((int)__shfl((int)inc, 63), MAXC);
    {
        uint m = 0;
#pragma unroll
        for (int q = 0; q < 4; ++q)
#pragma unroll
            for (int i = 0; i < 4; ++i)
                if (keys[q][i] >= T) {
                    const uint slot = base + m; ++m;
                    if (slot < MAXC) {
                        cvF[wid][slot] = __uint_as_float(keys[q][i]);
                        cjL[wid][slot] = q * 256 + lane * 4 + i;
                    }
                }
    }
    __builtin_amdgcn_wave_barrier();

    float sv = (lane < n) ? cvF[wid][lane] : -FLT_MAX;
    int   sj = (lane < n) ? cjL[wid][lane] : 0x7fffffff;
#pragma unroll
    for (int bk = 2; bk <= 64; bk <<= 1) {
#pragma unroll
        for (int bj = bk >> 1; bj >= 1; bj >>= 1) {
            const float pv = __shfl_xor(sv, bj);
            const int   pj = __shfl_xor(sj, bj);
            const bool iLow = (lane & bj) == 0;
            const bool dsc  = (lane & bk) == 0;
            const bool mineFirst = (sv > pv) || (sv == pv && sj < pj);
            if ((dsc == iLow) ? !mineFirst : mineFirst) { sv = pv; sj = pj; }
        }
    }
    const float cv19 = __shfl(sv, KSEL - 1);
    const int   cj19 = __shfl(sj, KSEL - 1);
    const float v20  = __shfl(sv, KSEL);
    const bool  amb  = (cv19 - v20 <= DELTA);

    uint m16 = 0;
    if (!amb) {
        if (lane < KSEL) { selv[wid][lane] = sv; selj[wid][lane] = sj; }
#pragma unroll
        for (int q = 0; q < 4; ++q)
#pragma unroll
            for (int i = 0; i < 4; ++i) {
                const float ev = __uint_as_float(keys[q][i]);
                const int   ej = q * 256 + lane * 4 + i;
                if (ev > cv19 || (ev == cv19 && ej <= cj19)) m16 |= 1u << (q * 4 + i);
            }
    } else {
        const float* xr = x + (size_t)b * IN_DIM;
        const int l4 = lane & 3;
#pragma unroll 1
        for (int p = 0; p < 4; ++p) {
            const int c = p * 16 + (lane >> 2);
            if (c < n) {
                const int j = cjL[wid][c];
                const float* wr = We + (size_t)j * IN_DIM;
                double s0 = 0.0, s1 = 0.0, s2 = 0.0, s3 = 0.0;
#pragma unroll 4
                for (int m = 0; m < 48; ++m) {
                    const int k = l4 * 4 + 16 * m;
                    const float4 w4 = *(const float4*)&wr[k];
                    const float4 x4 = *(const float4*)&xr[k];
                    s0 = fma((double)w4.x, (double)x4.x, s0);
                    s1 = fma((double)w4.y, (double)x4.y, s1);
                    s2 = fma((double)w4.z, (double)x4.z, s2);
                    s3 = fma((double)w4.w, (double)x4.w, s3);
                }
                double s = (s0 + s1) + (s2 + s3);
                s += __shfl_xor(s, 1);
                s += __shfl_xor(s, 2);
                if (l4 == 0) {
                    const double v = s + (double)be[j];
                    cvD[wid][c] = v > 0.0 ? v : 0.0;
                }
            }
        }
        __builtin_amdgcn_wave_barrier();
        double sd = (lane < n) ? cvD[wid][lane] : -1.0;
        int    dj = (lane < n) ? cjL[wid][lane] : 0x7fffffff;
#pragma unroll
        for (int bk = 2; bk <= 64; bk <<= 1) {
#pragma unroll
            for (int bj = bk >> 1; bj >= 1; bj >>= 1) {
                const double pd = __shfl_xor(sd, bj);
                const int    pj = __shfl_xor(dj, bj);
                const bool iLow = (lane & bj) == 0;
                const bool dsc  = (lane & bk) == 0;
                const bool mineFirst = (sd > pd) || (sd == pd && dj < pj);
                if ((dsc == iLow) ? !mineFirst : mineFirst) { sd = pd; dj = pj; }
            }
        }
        if (lane < KSEL) { selv[wid][lane] = (float)sd; selj[wid][lane] = dj; }
#pragma unroll 1
        for (int s = 0; s < KSEL; ++s) {
            const int js = __shfl(dj, s);
            const int d  = js - lane * 4;
            if (d >= 0 && (d & 255) < 4 && (d >> 8) < 4)
                m16 |= 1u << (((d >> 8) << 2) | (d & 3));
        }
    }

#pragma unroll
    for (int q = 0; q < 4; ++q) {
        float ov[4];
#pragma unroll
        for (int i = 0; i < 4; ++i)
            ov[i] = ((m16 >> (q * 4 + i)) & 1u) ? __uint_as_float(keys[q][i]) : 0.f;
        *(float4*)&hrow[q * 256 + lane * 4] = (float4){ov[0], ov[1], ov[2], ov[3]};
    }
    __builtin_amdgcn_wave_barrier();

    f32x4 a0 = {0.f,0.f,0.f,0.f}, a1 = {0.f,0.f,0.f,0.f}, a2 = {0.f,0.f,0.f,0.f};
    if (USE_BF) {
#pragma unroll 4
        for (int s = 0; s < KSEL; ++s) {
            const float v = selv[wid][s];
            const ushort* wr = WdTb + (size_t)selj[wid][s] * IN_DIM;
            const ushort4 w0 = *(const ushort4*)&wr[lane * 4];
            const ushort4 w1 = *(const ushort4*)&wr[lane * 4 + 256];
            const ushort4 w2 = *(const ushort4*)&wr[lane * 4 + 512];
            a0[0] = fmaf(v, bfu(w0.x), a0[0]); a0[1] = fmaf(v, bfu(w0.y), a0[1]);
            a0[2] = fmaf(v, bfu(w0.z), a0[2]); a0[3] = fmaf(v, bfu(w0.w), a0[3]);
            a1[0] = fmaf(v, bfu(w1.x), a1[0]); a1[1] = fmaf(v, bfu(w1.y), a1[1]);
            a1[2] = fmaf(v, bfu(w1.z), a1[2]); a1[3] = fmaf(v, bfu(w1.w), a1[3]);
            a2[0] = fmaf(v, bfu(w2.x), a2[0]); a2[1] = fmaf(v, bfu(w2.y), a2[1]);
            a2[2] = fmaf(v, bfu(w2.z), a2[2]); a2[3] = fmaf(v, bfu(w2.w), a2[3]);
        }
    } else {
        for (int s = 0; s < KSEL; ++s) {
            const float v = selv[wid][s];
            const int j = selj[wid][s];
#pragma unroll
            for (int i = 0; i < 4; ++i) {
                a0[i] = fmaf(v, Wd[(size_t)(lane * 4 + i) * HID + j], a0[i]);
                a1[i] = fmaf(v, Wd[(size_t)(lane * 4 + i + 256) * HID + j], a1[i]);
                a2[i] = fmaf(v, Wd[(size_t)(lane * 4 + i + 512) * HID + j], a2[i]);
            }
        }
    }
    float* rrow = recon + (size_t)b * IN_DIM;
    const float4 bd0 = *(const float4*)&bd[lane * 4];
    const float4 bd1 = *(const float4*)&bd[lane * 4 + 256];
    const float4 bd2 = *(const float4*)&bd[lane * 4 + 512];
    *(float4*)&rrow[lane * 4]       = (float4){a0[0] + bd0.x, a0[1] + bd0.y, a0[2] + bd0.z, a0[3] + bd0.w};
    *(float4*)&rrow[lane * 4 + 256] = (float4){a1[0] + bd1.x, a1[1] + bd1.y, a1[2] + bd1.z, a1[3] + bd1.w};
    *(float4*)&rrow[lane * 4 + 512] = (float4){a2[0] + bd2.x, a2[1] + bd2.y, a2[2] + bd2.z, a2[3] + bd2.w};
}

extern "C" void kernel_launch(void* const* d_in, const int* in_sizes, int n_in,
                              void* d_out, int out_size, void* d_ws, size_t ws_size,
                              hipStream_t stream)
{
    const float* x  = (const float*)d_in[0];
    const float* We = (const float*)d_in[1];
    const float* be = (const float*)d_in[2];
    const float* Wd = (const float*)d_in[3];
    const float* bd = (const float*)d_in[4];
    const int batch = in_sizes[0] / IN_DIM;   // 65536

    float* recon = (float*)d_out;
    float* h     = (float*)d_out + (size_t)batch * IN_DIM;

    const size_t WDB_BYTES = (size_t)IN_DIM * HID * sizeof(ushort);       // 1.5 MB
    const size_t WH_BYTES  = (size_t)HID * IN_DIM * sizeof(_Float16);     // 1.5 MB
    const size_t REC_BYTES = (size_t)batch * 2 * KSEL * sizeof(float);    // 10.5 MB
    const size_t XH_BYTES  = (size_t)batch * IN_DIM * sizeof(_Float16);   // 96.6 MB
    ushort*    WdTb = (ushort*)d_ws;
    _Float16*  wh   = (_Float16*)((char*)d_ws + WDB_BYTES);
    float*     rec  = (float*)((char*)d_ws + WDB_BYTES + WH_BYTES);
    _Float16*  xh   = (_Float16*)((char*)d_ws + WDB_BYTES + WH_BYTES + REC_BYTES);

    const bool have_wdb = (ws_size >= WDB_BYTES);
    const bool have_rec = (ws_size >= WDB_BYTES + WH_BYTES + REC_BYTES) && (batch % 4 == 0);
    const bool mfma_ok  = (ws_size >= WDB_BYTES + WH_BYTES + REC_BYTES + XH_BYTES)
                          && (batch % 128 == 0);

    if (have_wdb) {
        dim3 g(HID / 32, IN_DIM / 32), blk(32, 8);
        k_prep_wdb<<<g, blk, 0, stream>>>(Wd, WdTb);
    }
    if (mfma_ok) {
        k_split_x<<<(int)(((size_t)batch * IN_DIM / 8) / 256), 256, 0, stream>>>(x, xh);
        k_split_w<<<(HID * IN_DIM / 8) / 256, 256, 0, stream>>>(We, wh);
        dim3 g(HID / 128, batch / 128);
        k_encode_f16<<<g, 256, 0, stream>>>(xh, wh, be, h);
    } else {
        dim3 g(HID / 128, batch / 128);
        k_encode<<<g, 256, 0, stream>>>(x, We, be, h);
    }
    if (have_rec) {
        const int rpw = (batch % 32 == 0) ? 8 : 1;
        k_topk<<<batch / (4 * rpw), 256, 0, stream>>>(h, x, We, be, rec, rpw);
        k_decode<<<batch / 4, 256, 0, stream>>>(rec, WdTb, bd, recon);
    } else if (have_wdb) {
        k_topk_fused<1><<<batch / 4, 256, 0, stream>>>(h, x, We, be, WdTb, Wd, bd, recon);
    } else {
        k_topk_fused<0><<<batch / 4, 256, 0, stream>>>(h, x, We, be, WdTb, Wd, bd, recon);
    }
}

// Round 17
// 541.044 us; speedup vs baseline: 1.2613x; 1.2613x over previous
//
#include <hip/hip_runtime.h>
#include <cstdint>
#include <cfloat>

#define IN_DIM 768
#define HID    1024
#define KSEL   20
#define MAXC   64
#define TARGET 24
#define WSCALE 4096.0f
#define INV_WSCALE (1.0f / 4096.0f)
#define DELTA  3e-5f

typedef _Float16 f16x8 __attribute__((ext_vector_type(8)));
typedef float    f32x4 __attribute__((ext_vector_type(4)));

__device__ __forceinline__ void gload_lds16(const void* g, void* l) {
    __builtin_amdgcn_global_load_lds(
        (const __attribute__((address_space(1))) uint32_t*)g,
        (__attribute__((address_space(3))) uint32_t*)l, 16, 0, 0);
}

__device__ __forceinline__ float bfu(ushort u) { return __uint_as_float((uint)u << 16); }

// ---------------- K0: transpose W_dec [768][1024] -> WdTb [1024][768] bf16 (RNE) ----------------
__global__ void k_prep_wdb(const float* __restrict__ Wd, ushort* __restrict__ WdTb) {
    __shared__ float tile[32][33];
    const int j0 = blockIdx.x * 32;
    const int i0 = blockIdx.y * 32;
    const int tx = threadIdx.x;
    const int ty = threadIdx.y;
#pragma unroll
    for (int r = 0; r < 4; ++r)
        tile[ty + r * 8][tx] = Wd[(size_t)(i0 + ty + r * 8) * HID + (j0 + tx)];
    __syncthreads();
#pragma unroll
    for (int r = 0; r < 4; ++r) {
        const float v = tile[tx][ty + r * 8];
        uint u = __float_as_uint(v);
        u += 0x7FFFu + ((u >> 16) & 1u);           // round-to-nearest-even
        WdTb[(size_t)(j0 + ty + r * 8) * IN_DIM + (i0 + tx)] = (ushort)(u >> 16);
    }
}

// ---------------- split kernels: fp32 -> fp16 (W scaled by 4096) ----------------
__global__ __launch_bounds__(256) void k_split_x(const float* __restrict__ x,
                                                 _Float16* __restrict__ xh) {
    const size_t base = ((size_t)blockIdx.x * 256 + threadIdx.x) * 8;
    const float4 a = *(const float4*)(x + base);
    const float4 b = *(const float4*)(x + base + 4);
    f16x8 o;
    o[0] = (_Float16)a.x; o[1] = (_Float16)a.y; o[2] = (_Float16)a.z; o[3] = (_Float16)a.w;
    o[4] = (_Float16)b.x; o[5] = (_Float16)b.y; o[6] = (_Float16)b.z; o[7] = (_Float16)b.w;
    *(f16x8*)(xh + base) = o;
}

__global__ __launch_bounds__(256) void k_split_w(const float* __restrict__ w,
                                                 _Float16* __restrict__ wh) {
    const size_t base = ((size_t)blockIdx.x * 256 + threadIdx.x) * 8;
    const float4 a = *(const float4*)(w + base);
    const float4 b = *(const float4*)(w + base + 4);
    f16x8 o;
    o[0] = (_Float16)(a.x * WSCALE); o[1] = (_Float16)(a.y * WSCALE);
    o[2] = (_Float16)(a.z * WSCALE); o[3] = (_Float16)(a.w * WSCALE);
    o[4] = (_Float16)(b.x * WSCALE); o[5] = (_Float16)(b.y * WSCALE);
    o[6] = (_Float16)(b.z * WSCALE); o[7] = (_Float16)(b.w * WSCALE);
    *(f16x8*)(wh + base) = o;
}

// ---------------- K1: fp16 MFMA encode  h = relu((x16 @ w16^T)/4096 + be) ----------------
__global__ __launch_bounds__(256) void k_encode_f16(
    const _Float16* __restrict__ xh, const _Float16* __restrict__ wh,
    const float* __restrict__ be, float* __restrict__ h)
{
    __shared__ _Float16 lA[128 * 64];
    __shared__ _Float16 lB[128 * 64];
    const int t   = threadIdx.x;
    const int wid = t >> 6, l = t & 63;
    const int wm  = (wid >> 1) * 64, wn = (wid & 1) * 64;
    const int bn  = blockIdx.x * 128, bm = blockIdx.y * 128;

    const int lr = l >> 3;
    const int sl = (l & 7) ^ lr;
    const _Float16* gA = xh + (size_t)(bm + wid * 32 + lr) * IN_DIM + sl * 8;
    const _Float16* gB = wh + (size_t)(bn + wid * 32 + lr) * IN_DIM + sl * 8;
    char* la0 = (char*)lA + wid * 32 * 128;
    char* lb0 = (char*)lB + wid * 32 * 128;

    f32x4 acc[4][4];
#pragma unroll
    for (int i = 0; i < 4; ++i)
#pragma unroll
        for (int j = 0; j < 4; ++j) acc[i][j] = (f32x4){0.f, 0.f, 0.f, 0.f};

    const int row16 = l & 15, kb = l >> 4;

    for (int kt = 0; kt < IN_DIM; kt += 64) {
        __syncthreads();
#pragma unroll
        for (int i = 0; i < 4; ++i) {
            gload_lds16(gA + (size_t)i * 8 * IN_DIM + kt, la0 + i * 1024);
            gload_lds16(gB + (size_t)i * 8 * IN_DIM + kt, lb0 + i * 1024);
        }
        // explicit drain of global_load_lds before the consume barrier
        // (compiler normally emits this; made explicit after a post-timing
        //  single-row corruption flake in round 16)
        asm volatile("s_waitcnt vmcnt(0)" ::: "memory");
        __syncthreads();

        f16x8 af[4][2], bf[4][2];
#pragma unroll
        for (int f = 0; f < 4; ++f) {
            const int ra = wm + f * 16 + row16;
            const int pa = kb ^ (ra & 7);
            af[f][0] = *(const f16x8*)((const char*)lA + ra * 128 + pa * 16);
            af[f][1] = *(const f16x8*)((const char*)lA + ra * 128 + (pa ^ 4) * 16);
            const int rb = wn + f * 16 + row16;
            const int pb = kb ^ (rb & 7);
            bf[f][0] = *(const f16x8*)((const char*)lB + rb * 128 + pb * 16);
            bf[f][1] = *(const f16x8*)((const char*)lB + rb * 128 + (pb ^ 4) * 16);
        }
#pragma unroll
        for (int kh = 0; kh < 2; ++kh)
#pragma unroll
            for (int fm = 0; fm < 4; ++fm)
#pragma unroll
                for (int fn = 0; fn < 4; ++fn)
                    acc[fm][fn] = __builtin_amdgcn_mfma_f32_16x16x32_f16(
                        af[fm][kh], bf[fn][kh], acc[fm][fn], 0, 0, 0);
    }

    const int col = l & 15, rg = (l >> 4) * 4;
#pragma unroll
    for (int fn = 0; fn < 4; ++fn) {
        const int n = bn + wn + fn * 16 + col;
        const float bias = be[n];
#pragma unroll
        for (int fm = 0; fm < 4; ++fm) {
            const int m0 = bm + wm + fm * 16 + rg;
#pragma unroll
            for (int q = 0; q < 4; ++q)
                h[(size_t)(m0 + q) * HID + n] = fmaxf(fmaf(acc[fm][fn][q], INV_WSCALE, bias), 0.f);
        }
    }
}

// ---------------- K1-fallback: fp32 encode ----------------
__global__ __launch_bounds__(256, 2) void k_encode(
    const float* __restrict__ x, const float* __restrict__ We,
    const float* __restrict__ be, float* __restrict__ h)
{
    __shared__ float lx[16][132];
    __shared__ float lw[16][132];
    const int t  = threadIdx.x;
    const int tx = t & 15;
    const int ty = t >> 4;
    const int bn = blockIdx.x * 128;
    const int bm = blockIdx.y * 128;

    float acc[8][8];
#pragma unroll
    for (int r = 0; r < 8; ++r)
#pragma unroll
        for (int c = 0; c < 8; ++c) acc[r][c] = 0.f;

    const int sk = t & 15;
    const int sm = t >> 4;

    for (int kt = 0; kt < IN_DIM; kt += 16) {
        __syncthreads();
#pragma unroll
        for (int p = 0; p < 8; ++p) {
            const int m = sm + p * 16;
            lx[sk][m] = x [(size_t)(bm + m) * IN_DIM + (kt + sk)];
            lw[sk][m] = We[(size_t)(bn + m) * IN_DIM + (kt + sk)];
        }
        __syncthreads();
#pragma unroll
        for (int kk = 0; kk < 16; ++kk) {
            const float4 xa = *(const float4*)&lx[kk][ty * 8];
            const float4 xb = *(const float4*)&lx[kk][ty * 8 + 4];
            const float4 wa = *(const float4*)&lw[kk][tx * 4];
            const float4 wb = *(const float4*)&lw[kk][tx * 4 + 64];
            const float xf[8] = {xa.x, xa.y, xa.z, xa.w, xb.x, xb.y, xb.z, xb.w};
            const float wf[8] = {wa.x, wa.y, wa.z, wa.w, wb.x, wb.y, wb.z, wb.w};
#pragma unroll
            for (int r = 0; r < 8; ++r)
#pragma unroll
                for (int c = 0; c < 8; ++c)
                    acc[r][c] = fmaf(xf[r], wf[c], acc[r][c]);
        }
    }
#pragma unroll
    for (int r = 0; r < 8; ++r) {
        const size_t row = (size_t)(bm + ty * 8 + r) * HID;
#pragma unroll
        for (int c = 0; c < 4; ++c) {
            h[row + bn + tx * 4 + c]      = fmaxf(acc[r][c]     + be[bn + tx * 4 + c], 0.f);
            h[row + bn + 64 + tx * 4 + c] = fmaxf(acc[r][c + 4] + be[bn + 64 + tx * 4 + c], 0.f);
        }
    }
}

// ---------------- K2a: wave-per-row select, band-only f64 refine ----------------
__global__ __launch_bounds__(256, 8) void k_topk(
    float* __restrict__ h,
    const float* __restrict__ x,  const float* __restrict__ We,
    const float* __restrict__ be, float* __restrict__ rec)
{
    const int wid  = threadIdx.x >> 6;
    const int lane = threadIdx.x & 63;
    const int b    = blockIdx.x * 4 + wid;
    float* hrow = h + (size_t)b * HID;

    __shared__ float cvF[4][MAXC];
    __shared__ int   cjL[4][MAXC];

    uint keys[4][4];
#pragma unroll
    for (int q = 0; q < 4; ++q) {
        const uint4 k4 = *(const uint4*)&hrow[q * 256 + lane * 4];
        keys[q][0] = k4.x; keys[q][1] = k4.y; keys[q][2] = k4.z; keys[q][3] = k4.w;
    }

    // ---- Phase A: seeded ballot-bisect threshold: 24 <= count(key>=T) <= 64 ----
    uint mk = 0;
#pragma unroll
    for (int q = 0; q < 4; ++q)
#pragma unroll
        for (int i = 0; i < 4; ++i) mk = max(mk, keys[q][i]);
#pragma unroll
    for (int off = 1; off < 64; off <<= 1)
        mk = max(mk, (uint)__shfl_xor((int)mk, off));

    uint loT = 0u, hiT = mk;
    uint T  = __float_as_uint(0.55f * __uint_as_float(mk));
    bool found = false;
#pragma unroll 1
    for (int it = 0; it < 20; ++it) {
        int c = 0;
#pragma unroll
        for (int q = 0; q < 4; ++q)
#pragma unroll
            for (int i = 0; i < 4; ++i)
                c += (int)__popcll(__ballot(keys[q][i] >= T));
        if (c >= TARGET && c <= MAXC) { found = true; break; }
        if (c > MAXC) loT = T; else hiT = T;
        if (hiT - loT <= 1u) { T = loT; found = true; break; }
        T = (loT + hiT) >> 1;
    }
    if (!found) T = loT;
    const uint prefix = T;

    // ---- Phase B: compact candidates via shuffle prefix-sum ----
    uint cnt = 0;
#pragma unroll
    for (int q = 0; q < 4; ++q)
#pragma unroll
        for (int i = 0; i < 4; ++i) cnt += (keys[q][i] >= prefix) ? 1u : 0u;
    uint inc = cnt;
#pragma unroll
    for (int off = 1; off < 64; off <<= 1) {
        const uint o = __shfl_up(inc, off);
        if (lane >= off) inc += o;
    }
    const uint base = inc - cnt;
    const int  n    = min((int)__shfl((int)inc, 63), MAXC);
    {
        uint m = 0;
#pragma unroll
        for (int q = 0; q < 4; ++q)
#pragma unroll
            for (int i = 0; i < 4; ++i)
                if (keys[q][i] >= prefix) {
                    const uint slot = base + m; ++m;
                    if (slot < MAXC) {
                        cvF[wid][slot] = __uint_as_float(keys[q][i]);
                        cjL[wid][slot] = q * 256 + lane * 4 + i;
                    }
                }
    }
    // explicit LDS write->read ordering (guide rule #18 pattern): drain lgkm
    // and pin the scheduler so cross-lane LDS reads can't be hoisted.
    __builtin_amdgcn_wave_barrier();
    asm volatile("s_waitcnt lgkmcnt(0)" ::: "memory");
    __builtin_amdgcn_sched_barrier(0);

    const float myv = (lane < n) ? cvF[wid][lane] : -FLT_MAX;
    const int   myj = (lane < n) ? cjL[wid][lane] : 0x7fffffff;

    // ---- Phase C: 64-lane fp32 bitonic sort, desc by (v, then j asc) ----
    float sv = myv; int sj = myj;
#pragma unroll
    for (int bk = 2; bk <= 64; bk <<= 1) {
#pragma unroll
        for (int bj = bk >> 1; bj >= 1; bj >>= 1) {
            const float pv = __shfl_xor(sv, bj);
            const int   pj = __shfl_xor(sj, bj);
            const bool iLow = (lane & bj) == 0;
            const bool dsc  = (lane & bk) == 0;
            const bool mineFirst = (sv > pv) || (sv == pv && sj < pj);
            if ((dsc == iLow) ? !mineFirst : mineFirst) { sv = pv; sj = pj; }
        }
    }
    const float cv19 = __shfl(sv, KSEL - 1);
    const int   cj19 = __shfl(sj, KSEL - 1);
    const float v20  = __shfl(sv, KSEL);
    const bool  amb  = (cv19 - v20 <= DELTA);   // n >= 24 -> lane 20 real

    float* recrow = rec + (size_t)b * (2 * KSEL);
    uint m16 = 0;
    if (!amb) {
        if (lane < KSEL)
            *(float2*)&recrow[lane * 2] = (float2){sv, __int_as_float(sj)};
#pragma unroll
        for (int q = 0; q < 4; ++q)
#pragma unroll
            for (int i = 0; i < 4; ++i) {
                const float ev = __uint_as_float(keys[q][i]);
                const int   ej = q * 256 + lane * 4 + i;
                if (ev > cv19 || (ev == cv19 && ej <= cj19)) m16 |= 1u << (q * 4 + i);
            }
    } else {
        // ---- band-only f64 refine ----
        const bool inB = (lane < n) && (fabsf(myv - cv19) <= DELTA);
        const unsigned long long aMask = __ballot((lane < n) && (myv > cv19 + DELTA));
        const int kneed = KSEL - (int)__popcll(aMask);
        const float* xr = x + (size_t)b * IN_DIM;

        double dm = -1.0;
        unsigned long long bb = __ballot(inB);
#pragma unroll 1
        while (bb) {
            const int s = (int)__ffsll((long long)bb) - 1; bb &= bb - 1ull;
            const int j = __shfl(myj, s);
            const float* wr = We + (size_t)j * IN_DIM;
            double acc = 0.0;
#pragma unroll
            for (int m = 0; m < 12; ++m) {
                const int k = lane + (m << 6);
                acc = fma((double)wr[k], (double)xr[k], acc);
            }
#pragma unroll
            for (int off = 1; off < 64; off <<= 1) acc += __shfl_xor(acc, off);
            double v = acc + (double)be[j];
            v = v > 0.0 ? v : 0.0;
            if (lane == s) dm = v;
        }
        int brank = 0;
        unsigned long long bb2 = __ballot(inB);
#pragma unroll 1
        while (bb2) {
            const int s = (int)__ffsll((long long)bb2) - 1; bb2 &= bb2 - 1ull;
            const double ds = __shfl(dm, s);
            const int    js = __shfl(myj, s);
            if (inB && s != lane)
                brank += (ds > dm || (ds == dm && js < myj)) ? 1 : 0;
        }
        const bool selB = inB && (brank < kneed);
        const unsigned long long selMask = aMask | __ballot(selB);
        if ((selMask >> lane) & 1ull) {
            const int slot = (int)__popcll(selMask & ((1ull << lane) - 1ull));
            *(float2*)&recrow[slot * 2] = (float2){myv, __int_as_float(myj)};
        }
#pragma unroll
        for (int q = 0; q < 4; ++q)
#pragma unroll
            for (int i = 0; i < 4; ++i)
                if (__uint_as_float(keys[q][i]) > cv19 + DELTA) m16 |= 1u << (q * 4 + i);
        unsigned long long sb = __ballot(selB);
#pragma unroll 1
        while (sb) {
            const int s = (int)__ffsll((long long)sb) - 1; sb &= sb - 1ull;
            const int js = __shfl(myj, s);
            const int d  = js - lane * 4;
            if (d >= 0 && (d & 255) < 4 && (d >> 8) < 4)
                m16 |= 1u << (((d >> 8) << 2) | (d & 3));
        }
    }

    // ---- Phase D: masked h write ----
#pragma unroll
    for (int q = 0; q < 4; ++q) {
        float ov[4];
#pragma unroll
        for (int i = 0; i < 4; ++i)
            ov[i] = ((m16 >> (q * 4 + i)) & 1u) ? __uint_as_float(keys[q][i]) : 0.f;
        *(float4*)&hrow[q * 256 + lane * 4] = (float4){ov[0], ov[1], ov[2], ov[3]};
    }
}

// ---------------- K2b: record -> gather decode -> recon (chunked loads for ILP) ----------------
__global__ __launch_bounds__(256) void k_decode(
    const float* __restrict__ rec, const ushort* __restrict__ WdTb,
    const float* __restrict__ bd, float* __restrict__ recon)
{
    const int wid  = threadIdx.x >> 6;
    const int lane = threadIdx.x & 63;
    const int b    = blockIdx.x * 4 + wid;
    const float* rrec = rec + (size_t)b * (2 * KSEL);

    float v = 0.f; int jj = 0;
    if (lane < KSEL) {
        const float2 p = *(const float2*)&rrec[lane * 2];
        v = p.x; jj = __float_as_int(p.y);
    }

    f32x4 a0 = {0.f,0.f,0.f,0.f}, a1 = {0.f,0.f,0.f,0.f}, a2 = {0.f,0.f,0.f,0.f};
#pragma unroll
    for (int c = 0; c < 2; ++c) {
        ushort4 w0[10], w1[10], w2[10];
#pragma unroll
        for (int s = 0; s < 10; ++s) {
            const int js = __shfl(jj, c * 10 + s);
            const ushort* wr = WdTb + (size_t)js * IN_DIM + lane * 4;
            w0[s] = *(const ushort4*)wr;
            w1[s] = *(const ushort4*)(wr + 256);
            w2[s] = *(const ushort4*)(wr + 512);
        }
#pragma unroll
        for (int s = 0; s < 10; ++s) {
            const float vs = __shfl(v, c * 10 + s);
            a0[0] = fmaf(vs, bfu(w0[s].x), a0[0]); a0[1] = fmaf(vs, bfu(w0[s].y), a0[1]);
            a0[2] = fmaf(vs, bfu(w0[s].z), a0[2]); a0[3] = fmaf(vs, bfu(w0[s].w), a0[3]);
            a1[0] = fmaf(vs, bfu(w1[s].x), a1[0]); a1[1] = fmaf(vs, bfu(w1[s].y), a1[1]);
            a1[2] = fmaf(vs, bfu(w1[s].z), a1[2]); a1[3] = fmaf(vs, bfu(w1[s].w), a1[3]);
            a2[0] = fmaf(vs, bfu(w2[s].x), a2[0]); a2[1] = fmaf(vs, bfu(w2[s].y), a2[1]);
            a2[2] = fmaf(vs, bfu(w2[s].z), a2[2]); a2[3] = fmaf(vs, bfu(w2[s].w), a2[3]);
        }
    }
    float* rrow = recon + (size_t)b * IN_DIM;
    const float4 bd0 = *(const float4*)&bd[lane * 4];
    const float4 bd1 = *(const float4*)&bd[lane * 4 + 256];
    const float4 bd2 = *(const float4*)&bd[lane * 4 + 512];
    *(float4*)&rrow[lane * 4]       = (float4){a0[0] + bd0.x, a0[1] + bd0.y, a0[2] + bd0.z, a0[3] + bd0.w};
    *(float4*)&rrow[lane * 4 + 256] = (float4){a1[0] + bd1.x, a1[1] + bd1.y, a1[2] + bd1.z, a1[3] + bd1.w};
    *(float4*)&rrow[lane * 4 + 512] = (float4){a2[0] + bd2.x, a2[1] + bd2.y, a2[2] + bd2.z, a2[3] + bd2.w};
}

// ---------------- K2a-fallback: single-row fused select+decode (small-ws path) ----------------
template<int USE_BF>
__global__ __launch_bounds__(256) void k_topk_fused(
    float* __restrict__ h,
    const float* __restrict__ x,  const float* __restrict__ We,
    const float* __restrict__ be,
    const ushort* __restrict__ WdTb, const float* __restrict__ Wd,
    const float* __restrict__ bd, float* __restrict__ recon)
{
    const int wid  = threadIdx.x >> 6;
    const int lane = threadIdx.x & 63;
    const int b    = blockIdx.x * 4 + wid;
    float* hrow = h + (size_t)b * HID;

    __shared__ float  cvF [4][MAXC];
    __shared__ int    cjL [4][MAXC];
    __shared__ double cvD [4][MAXC];
    __shared__ float  selv[4][KSEL];
    __shared__ int    selj[4][KSEL];

    uint keys[4][4];
#pragma unroll
    for (int q = 0; q < 4; ++q) {
        const uint4 k4 = *(const uint4*)&hrow[q * 256 + lane * 4];
        keys[q][0] = k4.x; keys[q][1] = k4.y; keys[q][2] = k4.z; keys[q][3] = k4.w;
    }
    uint mk = 0;
#pragma unroll
    for (int q = 0; q < 4; ++q)
#pragma unroll
        for (int i = 0; i < 4; ++i) mk = max(mk, keys[q][i]);
#pragma unroll
    for (int off = 1; off < 64; off <<= 1)
        mk = max(mk, (uint)__shfl_xor((int)mk, off));

    uint loT = 0u, hiT = mk;
    uint T  = __float_as_uint(0.55f * __uint_as_float(mk));
    bool found = false;
#pragma unroll 1
    for (int it = 0; it < 20; ++it) {
        int c = 0;
#pragma unroll
        for (int q = 0; q < 4; ++q)
#pragma unroll
            for (int i = 0; i < 4; ++i)
                c += (int)__popcll(__ballot(keys[q][i] >= T));
        if (c >= TARGET && c <= MAXC) { found = true; break; }
        if (c > MAXC) loT = T; else hiT = T;
        if (hiT - loT <= 1u) { T = loT; found = true; break; }
        T = (loT + hiT) >> 1;
    }
    if (!found) T = loT;

    uint cnt = 0;
#pragma unroll
    for (int q = 0; q < 4; ++q)
#pragma unroll
        for (int i = 0; i < 4; ++i) cnt += (keys[q][i] >= T) ? 1u : 0u;
    uint inc = cnt;
#pragma unroll
    for (int off = 1; off < 64; off <<= 1) {
        const uint o = __shfl_up(inc, off);
        if (lane >= off) inc += o;
    }
    const uint base = inc - cnt;
    const int  n    = min((int)__shfl((int)inc, 63), MAXC);
    {
        uint m = 0;
#pragma unroll
        for (int q = 0; q < 4; ++q)
#pragma unroll
            for (int i = 0; i < 4; ++i)
                if (keys[q][i] >= T) {
                    const uint slot = base + m; ++m;
                    if (slot < MAXC) {
                        cvF[wid][slot] = __uint_as_float(keys[q][i]);
                        cjL[wid][slot] = q * 256 + lane * 4 + i;
                    }
                }
    }
    __builtin_amdgcn_wave_barrier();
    asm volatile("s_waitcnt lgkmcnt(0)" ::: "memory");
    __builtin_amdgcn_sched_barrier(0);

    float sv = (lane < n) ? cvF[wid][lane] : -FLT_MAX;
    int   sj = (lane < n) ? cjL[wid][lane] : 0x7fffffff;
#pragma unroll
    for (int bk = 2; bk <= 64; bk <<= 1) {
#pragma unroll
        for (int bj = bk >> 1; bj >= 1; bj >>= 1) {
            const float pv = __shfl_xor(sv, bj);
            const int   pj = __shfl_xor(sj, bj);
            const bool iLow = (lane & bj) == 0;
            const bool dsc  = (lane & bk) == 0;
            const bool mineFirst = (sv > pv) || (sv == pv && sj < pj);
            if ((dsc == iLow) ? !mineFirst : mineFirst) { sv = pv; sj = pj; }
        }
    }
    const float cv19 = __shfl(sv, KSEL - 1);
    const int   cj19 = __shfl(sj, KSEL - 1);
    const float v20  = __shfl(sv, KSEL);
    const bool  amb  = (cv19 - v20 <= DELTA);

    uint m16 = 0;
    if (!amb) {
        if (lane < KSEL) { selv[wid][lane] = sv; selj[wid][lane] = sj; }
#pragma unroll
        for (int q = 0; q < 4; ++q)
#pragma unroll
            for (int i = 0; i < 4; ++i) {
                const float ev = __uint_as_float(keys[q][i]);
                const int   ej = q * 256 + lane * 4 + i;
                if (ev > cv19 || (ev == cv19 && ej <= cj19)) m16 |= 1u << (q * 4 + i);
            }
    } else {
        const float* xr = x + (size_t)b * IN_DIM;
        const int l4 = lane & 3;
#pragma unroll 1
        for (int p = 0; p < 4; ++p) {
            const int c = p * 16 + (lane >> 2);
            if (c < n) {
                const int j = cjL[wid][c];
                const float* wr = We + (size_t)j * IN_DIM;
                double s0 = 0.0, s1 = 0.0, s2 = 0.0, s3 = 0.0;
#pragma unroll 4
                for (int m = 0; m < 48; ++m) {
                    const int k = l4 * 4 + 16 * m;
                    const float4 w4 = *(const float4*)&wr[k];
                    const float4 x4 = *(const float4*)&xr[k];
                    s0 = fma((double)w4.x, (double)x4.x, s0);
                    s1 = fma((double)w4.y, (double)x4.y, s1);
                    s2 = fma((double)w4.z, (double)x4.z, s2);
                    s3 = fma((double)w4.w, (double)x4.w, s3);
                }
                double s = (s0 + s1) + (s2 + s3);
                s += __shfl_xor(s, 1);
                s += __shfl_xor(s, 2);
                if (l4 == 0) {
                    const double v = s + (double)be[j];
                    cvD[wid][c] = v > 0.0 ? v : 0.0;
                }
            }
        }
        __builtin_amdgcn_wave_barrier();
        asm volatile("s_waitcnt lgkmcnt(0)" ::: "memory");
        __builtin_amdgcn_sched_barrier(0);
        double sd = (lane < n) ? cvD[wid][lane] : -1.0;
        int    dj = (lane < n) ? cjL[wid][lane] : 0x7fffffff;
#pragma unroll
        for (int bk = 2; bk <= 64; bk <<= 1) {
#pragma unroll
            for (int bj = bk >> 1; bj >= 1; bj >>= 1) {
                const double pd = __shfl_xor(sd, bj);
                const int    pj = __shfl_xor(dj, bj);
                const bool iLow = (lane & bj) == 0;
                const bool dsc  = (lane & bk) == 0;
                const bool mineFirst = (sd > pd) || (sd == pd && dj < pj);
                if ((dsc == iLow) ? !mineFirst : mineFirst) { sd = pd; dj = pj; }
            }
        }
        if (lane < KSEL) { selv[wid][lane] = (float)sd; selj[wid][lane] = dj; }
#pragma unroll 1
        for (int s = 0; s < KSEL; ++s) {
            const int js = __shfl(dj, s);
            const int d  = js - lane * 4;
            if (d >= 0 && (d & 255) < 4 && (d >> 8) < 4)
                m16 |= 1u << (((d >> 8) << 2) | (d & 3));
        }
    }

#pragma unroll
    for (int q = 0; q < 4; ++q) {
        float ov[4];
#pragma unroll
        for (int i = 0; i < 4; ++i)
            ov[i] = ((m16 >> (q * 4 + i)) & 1u) ? __uint_as_float(keys[q][i]) : 0.f;
        *(float4*)&hrow[q * 256 + lane * 4] = (float4){ov[0], ov[1], ov[2], ov[3]};
    }
    __builtin_amdgcn_wave_barrier();

    f32x4 a0 = {0.f,0.f,0.f,0.f}, a1 = {0.f,0.f,0.f,0.f}, a2 = {0.f,0.f,0.f,0.f};
    if (USE_BF) {
#pragma unroll 4
        for (int s = 0; s < KSEL; ++s) {
            const float v = selv[wid][s];
            const ushort* wr = WdTb + (size_t)selj[wid][s] * IN_DIM;
            const ushort4 w0 = *(const ushort4*)&wr[lane * 4];
            const ushort4 w1 = *(const ushort4*)&wr[lane * 4 + 256];
            const ushort4 w2 = *(const ushort4*)&wr[lane * 4 + 512];
            a0[0] = fmaf(v, bfu(w0.x), a0[0]); a0[1] = fmaf(v, bfu(w0.y), a0[1]);
            a0[2] = fmaf(v, bfu(w0.z), a0[2]); a0[3] = fmaf(v, bfu(w0.w), a0[3]);
            a1[0] = fmaf(v, bfu(w1.x), a1[0]); a1[1] = fmaf(v, bfu(w1.y), a1[1]);
            a1[2] = fmaf(v, bfu(w1.z), a1[2]); a1[3] = fmaf(v, bfu(w1.w), a1[3]);
            a2[0] = fmaf(v, bfu(w2.x), a2[0]); a2[1] = fmaf(v, bfu(w2.y), a2[1]);
            a2[2] = fmaf(v, bfu(w2.z), a2[2]); a2[3] = fmaf(v, bfu(w2.w), a2[3]);
        }
    } else {
        for (int s = 0; s < KSEL; ++s) {
            const float v = selv[wid][s];
            const int j = selj[wid][s];
#pragma unroll
            for (int i = 0; i < 4; ++i) {
                a0[i] = fmaf(v, Wd[(size_t)(lane * 4 + i) * HID + j], a0[i]);
                a1[i] = fmaf(v, Wd[(size_t)(lane * 4 + i + 256) * HID + j], a1[i]);
                a2[i] = fmaf(v, Wd[(size_t)(lane * 4 + i + 512) * HID + j], a2[i]);
            }
        }
    }
    float* rrow = recon + (size_t)b * IN_DIM;
    const float4 bd0 = *(const float4*)&bd[lane * 4];
    const float4 bd1 = *(const float4*)&bd[lane * 4 + 256];
    const float4 bd2 = *(const float4*)&bd[lane * 4 + 512];
    *(float4*)&rrow[lane * 4]       = (float4){a0[0] + bd0.x, a0[1] + bd0.y, a0[2] + bd0.z, a0[3] + bd0.w};
    *(float4*)&rrow[lane * 4 + 256] = (float4){a1[0] + bd1.x, a1[1] + bd1.y, a1[2] + bd1.z, a1[3] + bd1.w};
    *(float4*)&rrow[lane * 4 + 512] = (float4){a2[0] + bd2.x, a2[1] + bd2.y, a2[2] + bd2.z, a2[3] + bd2.w};
}

extern "C" void kernel_launch(void* const* d_in, const int* in_sizes, int n_in,
                              void* d_out, int out_size, void* d_ws, size_t ws_size,
                              hipStream_t stream)
{
    const float* x  = (const float*)d_in[0];
    const float* We = (const float*)d_in[1];
    const float* be = (const float*)d_in[2];
    const float* Wd = (const float*)d_in[3];
    const float* bd = (const float*)d_in[4];
    const int batch = in_sizes[0] / IN_DIM;   // 65536

    float* recon = (float*)d_out;
    float* h     = (float*)d_out + (size_t)batch * IN_DIM;

    const size_t WDB_BYTES = (size_t)IN_DIM * HID * sizeof(ushort);       // 1.5 MB
    const size_t WH_BYTES  = (size_t)HID * IN_DIM * sizeof(_Float16);     // 1.5 MB
    const size_t REC_BYTES = (size_t)batch * 2 * KSEL * sizeof(float);    // 10.5 MB
    const size_t XH_BYTES  = (size_t)batch * IN_DIM * sizeof(_Float16);   // 96.6 MB
    ushort*    WdTb = (ushort*)d_ws;
    _Float16*  wh   = (_Float16*)((char*)d_ws + WDB_BYTES);
    float*     rec  = (float*)((char*)d_ws + WDB_BYTES + WH_BYTES);
    _Float16*  xh   = (_Float16*)((char*)d_ws + WDB_BYTES + WH_BYTES + REC_BYTES);

    const bool have_wdb = (ws_size >= WDB_BYTES);
    const bool have_rec = (ws_size >= WDB_BYTES + WH_BYTES + REC_BYTES) && (batch % 4 == 0);
    const bool mfma_ok  = (ws_size >= WDB_BYTES + WH_BYTES + REC_BYTES + XH_BYTES)
                          && (batch % 128 == 0);

    if (have_wdb) {
        dim3 g(HID / 32, IN_DIM / 32), blk(32, 8);
        k_prep_wdb<<<g, blk, 0, stream>>>(Wd, WdTb);
    }
    if (mfma_ok) {
        k_split_x<<<(int)(((size_t)batch * IN_DIM / 8) / 256), 256, 0, stream>>>(x, xh);
        k_split_w<<<(HID * IN_DIM / 8) / 256, 256, 0, stream>>>(We, wh);
        dim3 g(HID / 128, batch / 128);
        k_encode_f16<<<g, 256, 0, stream>>>(xh, wh, be, h);
        k_topk<<<batch / 4, 256, 0, stream>>>(h, x, We, be, rec);
        k_decode<<<batch / 4, 256, 0, stream>>>(rec, WdTb, bd, recon);
    } else if (have_wdb && have_rec) {
        dim3 g(HID / 128, batch / 128);
        k_encode<<<g, 256, 0, stream>>>(x, We, be, h);
        k_topk<<<batch / 4, 256, 0, stream>>>(h, x, We, be, rec);
        k_decode<<<batch / 4, 256, 0, stream>>>(rec, WdTb, bd, recon);
    } else if (have_wdb) {
        dim3 g(HID / 128, batch / 128);
        k_encode<<<g, 256, 0, stream>>>(x, We, be, h);
        k_topk_fused<1><<<batch / 4, 256, 0, stream>>>(h, x, We, be, WdTb, Wd, bd, recon);
    } else {
        dim3 g(HID / 128, batch / 128);
        k_encode<<<g, 256, 0, stream>>>(x, We, be, h);
        k_topk_fused<0><<<batch / 4, 256, 0, stream>>>(h, x, We, be, WdTb, Wd, bd, recon);
    }
}